// Round 12
// baseline (208.021 us; speedup 1.0000x reference)
//
#include <hip/hip_runtime.h>

// MinVarianceWeightsLayer: for each of B SPD 64x64 fp32 matrices S,
// solve S z = 1, output w = z / sum(z) as [B, 64, 1] fp32.
//
// ROUND-20: TWO WAVES PER MATRIX (column-split Gauss-Jordan).
// Diagnosis closed in r19: the r14-lineage plateau (~192us bench, ~70us
// kernel) is NOT pipe-bound (DS-conflict fix: null; ILP deferral: null;
// every waves_per_eu cell: null/worse). Measured root cause: with 64
// floats/lane of state the allocator inflates the instruction stream
// ~1.85x with copies (r13: 140k issue-cyc/SIMD vs 75k static) AND
// residency is stuck at 2.25-3 waves/SIMD. Both fall to halving state.
// Design: block = 128 thr = 2 waves = ONE matrix. Wave w owns 4-col
// blocks cb (cb&1==w), 32 cols/lane = 16 v2f = 32 floats of state ->
// ~60 VGPR natural, no shuttles, up to 6 waves/EU resident (4,6).
// Panel P (cols 4P..4P+3) owned by wave P&1: owner runs the in-panel
// GJ chain, publishes nf[4][64] + el[4][64] (el = symmetric-trick
// u-source, stride-1 LDS, conflict-free), ONE barrier; then BOTH waves
// rank-4-update their own trailing slots with readlane broadcasts
// (u_c(j) = rlane(el[c], j) -- works in both waves since el was read
// per-lane). b replicated (non-owner replays 4 fma); d captured by the
// col-owner; epilogue exchanges z via LDS, wave 0 reduces + writes.
// Buffer safety: nfb/elb indexed by owner parity; panel P's readers
// finish before barrier(P+1), P+2's writes start after it.
// Same per-column arithmetic as validated r9-r19 (absmax 2.441e-4).

#define NN 64

typedef float v2f __attribute__((ext_vector_type(2)));
typedef float v4f __attribute__((ext_vector_type(4)));

template <int I> struct ic { static constexpr int value = I; };

template <int Start, int End, typename F>
__device__ __forceinline__ void static_for(F&& f) {
    if constexpr (Start < End) {
        f(ic<Start>{});
        static_for<Start + 1, End>(static_cast<F&&>(f));
    }
}

__device__ __forceinline__ float rlane(float v, int l) {
    return __int_as_float(__builtin_amdgcn_readlane(__float_as_int(v), l));
}

__device__ __forceinline__ float frcp(float x) {
#if __has_builtin(__builtin_amdgcn_rcpf)
    return __builtin_amdgcn_rcpf(x);   // ~1 ulp; plenty vs 2e-3 abs threshold
#else
    return 1.0f / x;
#endif
}

__global__
__attribute__((amdgpu_flat_work_group_size(128, 128), amdgpu_waves_per_eu(4, 6)))
void minvar_kernel(const float* __restrict__ sigma,
                   float* __restrict__ out,
                   int batch) {
    __shared__ float nfb[2][4][NN];   // [owner][col-in-panel][row]
    __shared__ float elb[2][4][NN];   // u-source (= el_c per row, symmetric trick)
    __shared__ float zb[NN];

    const int lane = threadIdx.x & 63;
    const int w    = threadIdx.x >> 6;       // 0/1: owns 4-col blocks cb with cb&1==w
    const int bid  = blockIdx.x;
    if (bid >= batch) return;                // uniform per block -> barrier-safe

    const float* __restrict__ p = sigma + (size_t)bid * (NN * NN) + (size_t)lane * NN;

    // lane = row; local pair-slot m = 2g+h covers global cols 4*(2g+w)+2h+{0,1}
    v2f r[16];
    auto load_half = [&](auto Wc) {
        constexpr int W = decltype(Wc)::value;
        static_for<0, 8>([&](auto gc) {
            constexpr int g = decltype(gc)::value;
            const v4f v = *reinterpret_cast<const v4f*>(p + 4 * (2 * g + W));
            r[2 * g]     = v2f{v.x, v.y};
            r[2 * g + 1] = v2f{v.z, v.w};
        });
    };
    if (w == 0) load_half(ic<0>{}); else load_half(ic<1>{});

    float b = 1.0f;   // RHS (replicated in both waves, updated identically)
    float d = 1.0f;   // pivot diag; set once, in the wave owning col==lane

    static_for<0, 16>([&](auto pc) {
        constexpr int P     = decltype(pc)::value;
        constexpr int owner = P & 1;
        constexpr int k0    = 4 * P;
        constexpr int m0    = 2 * (P >> 1);   // owner-local panel slots m0, m0+1

        float el[4], nf[4];                   // compile-time indexed -> VGPRs

        if (w == owner) {
            // ---- phase 1: in-panel GJ chain (owner only), publish as we go ----
            static_for<0, 4>([&](auto cc) {
                constexpr int c  = decltype(cc)::value;
                constexpr int k  = k0 + c;
                constexpr int mm = m0 + (c >> 1);
                const float e = (c & 1) ? r[mm].y : r[mm].x;
                elb[owner][c][lane] = e;                 // stride-1, conflict-free
                const float piv = rlane(e, k);
                const float f   = (lane != k) ? (-e * frcp(piv)) : 0.0f;
                nfb[owner][c][lane] = f;
                d = (lane == k) ? e : d;
                b = fmaf(f, rlane(b, k), b);
                static_for<c + 1, 4>([&](auto jc) {      // update rest of panel
                    constexpr int J  = decltype(jc)::value;
                    constexpr int mj = m0 + (J >> 1);
                    float v = (J & 1) ? r[mj].y : r[mj].x;
                    v = fmaf(f, rlane(v, k), v);
                    if constexpr (J & 1) r[mj].y = v; else r[mj].x = v;
                });
                el[c] = e; nf[c] = f;
            });
        }
        __syncthreads();
        if (w != owner) {
            // fetch published nf/el (per-lane, stride-1) and replay b-chain
            static_for<0, 4>([&](auto cc) {
                constexpr int c = decltype(cc)::value;
                nf[c] = nfb[owner][c][lane];
                el[c] = elb[owner][c][lane];
            });
            static_for<0, 4>([&](auto cc) {
                constexpr int c = decltype(cc)::value;
                b = fmaf(nf[c], rlane(b, k0 + c), b);
            });
        }

        // ---- rank-4 trailing update on own slots (both waves) ----
        // u_c(j) = A[k_c][j] = (symmetry) el_c at row j = rlane(el[c], j).
        auto trail = [&](auto Wc, auto Sc) {
            constexpr int W = decltype(Wc)::value;
            constexpr int S = decltype(Sc)::value;
            static_for<S, 16>([&](auto mc) {
                constexpr int m  = decltype(mc)::value;
                constexpr int j0 = 4 * (2 * (m >> 1) + W) + 2 * (m & 1);
                constexpr int j1 = j0 + 1;
                float ax = r[m].x, ay = r[m].y;
                static_for<0, 4>([&](auto cc) {
                    constexpr int c = decltype(cc)::value;
                    ax = fmaf(nf[c], rlane(el[c], j0), ax);
                    ay = fmaf(nf[c], rlane(el[c], j1), ay);
                });
                r[m] = v2f{ax, ay};
            });
        };
        // owner trailing starts after its panel slots; non-owner's first
        // trailing slot: P even -> m0 (its cb=P+1), P odd -> m0+2.
        if (w == owner) trail(ic<owner>{}, ic<m0 + 2>{});
        else            trail(ic<1 - owner>{}, ic<(P & 1) ? (m0 + 2) : m0>{});
    });

    // ---- diagonal system: z = b / d (valid where this wave owns col==lane) ----
    const float z = b * frcp(d);
    if (((lane >> 2) & 1) == w) zb[lane] = z;
    __syncthreads();
    if (w == 0) {
        const float zi = zb[lane];
        float tot = zi;
        #pragma unroll
        for (int off = 32; off >= 1; off >>= 1)
            tot += __shfl_xor(tot, off, 64);
        out[(size_t)bid * NN + lane] = zi * frcp(tot);
    }
}

extern "C" void kernel_launch(void* const* d_in, const int* in_sizes, int n_in,
                              void* d_out, int out_size, void* d_ws, size_t ws_size,
                              hipStream_t stream) {
    const float* sigma = (const float*)d_in[0];
    float* out = (float*)d_out;
    const int batch = in_sizes[0] / (NN * NN);   // 8192
    minvar_kernel<<<batch, 128, 0, stream>>>(sigma, out, batch);
}

// Round 13
// 192.535 us; speedup vs baseline: 1.0804x; 1.0804x over previous
//
#include <hip/hip_runtime.h>

// MinVarianceWeightsLayer: for each of B SPD 64x64 fp32 matrices S,
// solve S z = 1, output w = z / sum(z) as [B, 64, 1] fp32.
//
// ROUND-21 (FINAL): byte-identical revert to r15, the session's measured
// best (bench 192.13us, kernel ~70us, below the harness's 77us fill
// dispatches). Ledger: r9 all-LDS 87us; r10/r13 all-readlane 92/88.6;
// r11 dual-pipe unpipelined 84; r12/r14/r15 pipelined dual-pipe ~70
// (bench 192-194); r16-r20 (2-mat/wave, (3,6), (4,4), conflict-pad,
// 2-wave-split) all null or negative. Terminal diagnosis: the kernel is
// NOT pipe-bound (DS-conflict fix null, DS 38us/CU and VALU 40us/SIMD
// both below the 70us observed); it is bound by toolchain instruction-
// stream inflation (measured 1.9-2.2x static instr count across FOUR
// structures, incl. r20 at only 32 floats/lane state) plus residency
// capped at ~2.25-3 waves/SIMD. No HIP-source knob moved either factor.
// Structure: Gauss-Jordan, one wave/matrix, no barriers. Cross-panel
// software pipeline: panel P-1's trailing update is split into group0
// (slots 2P..2P+5, same iteration) and REST (slots 2P+6.., deferred into
// iteration P, interleaved between phase-1 columns). Dual-pipe rank-4
// update split x=1/2: per group of 8 slots, {issue 4 slots' uniform
// ds_read_b128} -> {4 readlane slots cover DS latency} -> {consume with
// v_pk_fma}. Symmetric trailing block => published column u_c(j) ==
// el_c at lane j. waves_per_eu(3,3) = proven-optimal occupancy cell.
// Validated absmax 2.441e-4 across r9-r20.

#define NN 64

typedef float v2f __attribute__((ext_vector_type(2)));
typedef float v4f __attribute__((ext_vector_type(4)));

template <int I> struct ic { static constexpr int value = I; };

template <int Start, int End, typename F>
__device__ __forceinline__ void static_for(F&& f) {
    if constexpr (Start < End) {
        f(ic<Start>{});
        static_for<Start + 1, End>(static_cast<F&&>(f));
    }
}

__device__ __forceinline__ float rlane(float v, int lane) {
    return __int_as_float(__builtin_amdgcn_readlane(__float_as_int(v), lane));
}

__device__ __forceinline__ float frcp(float x) {
#if __has_builtin(__builtin_amdgcn_rcpf)
    return __builtin_amdgcn_rcpf(x);   // ~1 ulp; plenty vs 2e-3 abs threshold
#else
    return 1.0f / x;
#endif
}

__device__ __forceinline__ v2f fma2(v2f a, v2f b, v2f c) {
#if __has_builtin(__builtin_elementwise_fma)
    return __builtin_elementwise_fma(a, b, c);   // -> v_pk_fma_f32
#else
    v2f r; r.x = fmaf(a.x, b.x, c.x); r.y = fmaf(a.y, b.y, c.y); return r;
#endif
}

__global__
__attribute__((amdgpu_flat_work_group_size(256, 256), amdgpu_waves_per_eu(3, 3)))
void minvar_kernel(const float* __restrict__ sigma,
                   float* __restrict__ out,
                   int batch) {
    // [wave][panel parity][ m*8 + c*2 + par ] : u_c[2m+par]
    __shared__ float pb[4][2][2 * NN * 4 / 2];   // 4 waves x 2 x 256 floats = 8 KB

    const int lane = threadIdx.x & 63;
    const int wid  = threadIdx.x >> 6;     // 4 waves/block, 1 matrix each
    const int bid  = blockIdx.x * 4 + wid;
    if (bid >= batch) return;              // no barriers anywhere -> safe

    const float* __restrict__ p = sigma + (size_t)bid * (NN * NN) + (size_t)lane * NN;

    // lane i's row as 32 float2 pairs (all indices compile-time -> VGPRs)
    v2f r[NN / 2];
    static_for<0, NN / 4>([&](auto j4c) {
        constexpr int j4 = decltype(j4c)::value;
        v4f v = reinterpret_cast<const v4f*>(p)[j4];
        r[2 * j4 + 0] = v2f{v.x, v.y};
        r[2 * j4 + 1] = v2f{v.z, v.w};
    });

    float b = 1.0f;                        // RHS: ones
    float d = 1.0f;                        // this lane's pivot (set exactly once)
    const int wbase = (lane >> 1) * 8 + (lane & 1);   // scatter-write index

    // carried prev-panel broadcast state (panel P-1's el/nf), set at the
    // end of each iteration's group0
    float el0p = 0.f, el1p = 0.f, el2p = 0.f, el3p = 0.f;
    float nf0p = 0.f, nf1p = 0.f, nf2p = 0.f, nf3p = 0.f;

    static_for<0, 16>([&](auto pc) {
        constexpr int P  = decltype(pc)::value;
        constexpr int k0 = 4 * P;
        constexpr int m0 = 2 * P;          // pair-slots m0, m0+1 are the panel
        float* __restrict__ wb  = &pb[wid][P & 1][0];        // panel P publishes
        float* __restrict__ wbp = &pb[wid][(P & 1) ^ 1][0];  // panel P-1's data

        // ---- deferred trailing update of panel P-1: slots 2P+6..31,
        //      executed as up to 3 groups interleaved between phase-1 cols.
        //      Each group: 4 LDS-prefetch slots + 4 readlane slots (A/B/C).
        auto do_rest_group = [&](auto Gc) {
            constexpr int G = decltype(Gc)::value;
            constexpr int s = 2 * P + 6 + 8 * G;
            if constexpr (P >= 1 && s < NN / 2) {
                constexpr int e = (s + 8 < NN / 2) ? (s + 8) : (NN / 2);
                const v2f n0 = v2f{nf0p, nf0p}, n1 = v2f{nf1p, nf1p};
                const v2f n2 = v2f{nf2p, nf2p}, n3 = v2f{nf3p, nf3p};
                v4f lo[4], hi[4];
                // pass A: issue DS reads (q = 0..3)
                static_for<s, e>([&](auto mc) {
                    constexpr int m = decltype(mc)::value;
                    constexpr int q = m - s;
                    if constexpr (q < 4) {
                        lo[q] = *reinterpret_cast<const v4f*>(wbp + 8 * m);
                        hi[q] = *reinterpret_cast<const v4f*>(wbp + 8 * m + 4);
                    }
                });
                // pass B: readlane slots (q = 4..7), independent of DS
                static_for<s, e>([&](auto mc) {
                    constexpr int m = decltype(mc)::value;
                    constexpr int q = m - s;
                    if constexpr (q >= 4) {
                        constexpr int j0 = 2 * m, j1 = 2 * m + 1;
                        float ax = r[m].x, ay = r[m].y;
                        ax = fmaf(nf0p, rlane(el0p, j0), ax);
                        ay = fmaf(nf0p, rlane(el0p, j1), ay);
                        ax = fmaf(nf1p, rlane(el1p, j0), ax);
                        ay = fmaf(nf1p, rlane(el1p, j1), ay);
                        ax = fmaf(nf2p, rlane(el2p, j0), ax);
                        ay = fmaf(nf2p, rlane(el2p, j1), ay);
                        ax = fmaf(nf3p, rlane(el3p, j0), ax);
                        ay = fmaf(nf3p, rlane(el3p, j1), ay);
                        r[m] = v2f{ax, ay};
                    }
                });
                // pass C: consume prefetched LDS data (q = 0..3)
                static_for<s, e>([&](auto mc) {
                    constexpr int m = decltype(mc)::value;
                    constexpr int q = m - s;
                    if constexpr (q < 4) {
                        v2f acc = r[m];
                        acc = fma2(n0, v2f{lo[q].x, lo[q].y}, acc);
                        acc = fma2(n1, v2f{lo[q].z, lo[q].w}, acc);
                        acc = fma2(n2, v2f{hi[q].x, hi[q].y}, acc);
                        acc = fma2(n3, v2f{hi[q].z, hi[q].w}, acc);
                        r[m] = acc;
                    }
                });
            }
        };

        // ---- phase-1 column 0 (slots m0,m0+1 only; indep of REST) ----
        const float el0  = r[m0].x;                    // A[i][k0] (pre-panel)
        if constexpr (P < 15) wb[wbase + 0] = el0;     // publish early
        const float piv0 = rlane(el0, k0);
        const float nf0  = (lane != k0) ? (-el0 * frcp(piv0)) : 0.0f;
        d = (lane == k0) ? el0 : d;
        b = fmaf(nf0, rlane(b, k0), b);
        const float u01 = rlane(r[m0].y,     k0);
        const float u02 = rlane(r[m0 + 1].x, k0);
        const float u03 = rlane(r[m0 + 1].y, k0);
        r[m0].y     = fmaf(nf0, u01, r[m0].y);
        r[m0 + 1].x = fmaf(nf0, u02, r[m0 + 1].x);
        r[m0 + 1].y = fmaf(nf0, u03, r[m0 + 1].y);

        do_rest_group(ic<0>{});   // panel P-1 trailing, group 0

        // ---- phase-1 column 1 ----
        const float el1  = r[m0].y;                    // A[i][k0+1] after c0
        if constexpr (P < 15) wb[wbase + 2] = el1;
        const float piv1 = rlane(el1, k0 + 1);
        const float nf1  = (lane != k0 + 1) ? (-el1 * frcp(piv1)) : 0.0f;
        d = (lane == k0 + 1) ? el1 : d;
        b = fmaf(nf1, rlane(b, k0 + 1), b);
        const float u12 = rlane(r[m0 + 1].x, k0 + 1);
        const float u13 = rlane(r[m0 + 1].y, k0 + 1);
        r[m0 + 1].x = fmaf(nf1, u12, r[m0 + 1].x);
        r[m0 + 1].y = fmaf(nf1, u13, r[m0 + 1].y);

        do_rest_group(ic<1>{});   // panel P-1 trailing, group 1

        // ---- phase-1 column 2 ----
        const float el2  = r[m0 + 1].x;                // A[i][k0+2] after c0,c1
        if constexpr (P < 15) wb[wbase + 4] = el2;
        const float piv2 = rlane(el2, k0 + 2);
        const float nf2  = (lane != k0 + 2) ? (-el2 * frcp(piv2)) : 0.0f;
        d = (lane == k0 + 2) ? el2 : d;
        b = fmaf(nf2, rlane(b, k0 + 2), b);
        const float u23 = rlane(r[m0 + 1].y, k0 + 2);
        r[m0 + 1].y = fmaf(nf2, u23, r[m0 + 1].y);

        do_rest_group(ic<2>{});   // panel P-1 trailing, group 2

        // ---- phase-1 column 3 ----
        const float el3  = r[m0 + 1].y;                // A[i][k0+3] after c0..c2
        if constexpr (P < 15) wb[wbase + 6] = el3;
        const float piv3 = rlane(el3, k0 + 3);
        const float nf3  = (lane != k0 + 3) ? (-el3 * frcp(piv3)) : 0.0f;
        d = (lane == k0 + 3) ? el3 : d;
        b = fmaf(nf3, rlane(b, k0 + 3), b);

        // ---- group0(P): slots m0+2..m0+7 (3 LDS + 3 readlane), kept in
        //      this iteration so phase-1(P+1) finds slots 2P+2,2P+3 done.
        if constexpr (P < 15) {
            constexpr int s0 = m0 + 2;
            constexpr int e0 = (m0 + 8 < NN / 2) ? (m0 + 8) : (NN / 2);
            const v2f n0 = v2f{nf0, nf0}, n1 = v2f{nf1, nf1};
            const v2f n2 = v2f{nf2, nf2}, n3 = v2f{nf3, nf3};
            v4f lo0[3], hi0[3];
            // pass A: issue DS reads (q = 0..2)
            static_for<s0, e0>([&](auto mc) {
                constexpr int m = decltype(mc)::value;
                constexpr int q = m - s0;
                if constexpr (q < 3) {
                    lo0[q] = *reinterpret_cast<const v4f*>(wb + 8 * m);
                    hi0[q] = *reinterpret_cast<const v4f*>(wb + 8 * m + 4);
                }
            });
            // pass B: readlane slots (q = 3..5)
            static_for<s0, e0>([&](auto mc) {
                constexpr int m = decltype(mc)::value;
                constexpr int q = m - s0;
                if constexpr (q >= 3) {
                    constexpr int j0 = 2 * m, j1 = 2 * m + 1;
                    float ax = r[m].x, ay = r[m].y;
                    ax = fmaf(nf0, rlane(el0, j0), ax);
                    ay = fmaf(nf0, rlane(el0, j1), ay);
                    ax = fmaf(nf1, rlane(el1, j0), ax);
                    ay = fmaf(nf1, rlane(el1, j1), ay);
                    ax = fmaf(nf2, rlane(el2, j0), ax);
                    ay = fmaf(nf2, rlane(el2, j1), ay);
                    ax = fmaf(nf3, rlane(el3, j0), ax);
                    ay = fmaf(nf3, rlane(el3, j1), ay);
                    r[m] = v2f{ax, ay};
                }
            });
            // pass C: consume prefetched LDS data
            static_for<s0, e0>([&](auto mc) {
                constexpr int m = decltype(mc)::value;
                constexpr int q = m - s0;
                if constexpr (q < 3) {
                    v2f acc = r[m];
                    acc = fma2(n0, v2f{lo0[q].x, lo0[q].y}, acc);
                    acc = fma2(n1, v2f{lo0[q].z, lo0[q].w}, acc);
                    acc = fma2(n2, v2f{hi0[q].x, hi0[q].y}, acc);
                    acc = fma2(n3, v2f{hi0[q].z, hi0[q].w}, acc);
                    r[m] = acc;
                }
            });
            // carry panel-P broadcast state into iteration P+1's REST
            el0p = el0; el1p = el1; el2p = el2; el3p = el3;
            nf0p = nf0; nf1p = nf1; nf2p = nf2; nf3p = nf3;
        }
    });

    // ---- diagonal system: z = b / d (no back-substitution in Gauss-Jordan) ----
    const float z = b * frcp(d);

    // ---- normalize: w = z / sum(z) ----
    float tot = z;
    #pragma unroll
    for (int off = 32; off >= 1; off >>= 1)
        tot += __shfl_xor(tot, off, 64);

    out[(size_t)bid * NN + lane] = z * frcp(tot);
}

extern "C" void kernel_launch(void* const* d_in, const int* in_sizes, int n_in,
                              void* d_out, int out_size, void* d_ws, size_t ws_size,
                              hipStream_t stream) {
    const float* sigma = (const float*)d_in[0];
    float* out = (float*)d_out;
    const int batch  = in_sizes[0] / (NN * NN);   // 8192
    const int blocks = (batch + 3) / 4;           // 4 matrices per 256-thr block
    minvar_kernel<<<blocks, 256, 0, stream>>>(sigma, out, batch);
}